// Round 15
// baseline (1821.649 us; speedup 1.0000x reference)
//
#include <hip/hip_runtime.h>

// MultiHeadAttentionCell: B=2, L=2048, H=16, C=64, fp32 in/out.
// Outputs (concat in d_out): context_vec (B,L,H*C)=4194304 | scores (B,H,L,L)=134217728 | attn (B,H,L,L)=134217728
// scores = Q K^T + edge ; attn = softmax(where(mask, scores/8, -1e18)) * mask ; ctx = attn @ V
//
// Round 15: OCCUPANCY test on the barrier-free R14 structure. Facts: time ~690-880us
// invariant to bytes (1.9-2.7GB) AND sync structure (barriers or none) -> latency-bound.
// All designs since R10 had exactly 4096 waves (16 rows/wave) = 16 waves/CU = 50% occ.
// Fix: split j 2-way per wave -> 8192 waves = 32/CU = 100% occ (VGPR=64 = the 8-wave
// limit, enforced via __launch_bounds__(256,8)). k_A: end-of-kernel LDS sum of the two
// j-half row-sums. k_B: end-of-kernel 8KB LDS reduce of the two partial PV accumulators.
// No per-iteration barriers. Otherwise byte-identical to R14:
//   k_prep: Kb = bf16(K); Vt = bf16(V^T) [b][h][c][j] in d_ws (RTNE == in-kernel path).
//   k_A   : swapped QK^T from per-lane Kb frags; writes sc; row-sum l -> inv.
//   k_B   : reads sc back (exact f32); w=exp(sc/8)*inv*mask -> attn; PV -> ctx.

typedef __attribute__((ext_vector_type(8))) short bf16x8;  // 8 bf16 = 4 VGPRs
typedef __attribute__((ext_vector_type(4))) float f32x4;
typedef __attribute__((ext_vector_type(4))) int   i32x4;

#define LQ 2048
#define NH 16
#define CD 64
#define NHC (NH*CD)

__device__ inline short f2bf(float x) {
    union { float f; unsigned u; } v; v.f = x;
    unsigned r = v.u + 0x7FFFu + ((v.u >> 16) & 1u);   // RTNE
    return (short)(r >> 16);
}

__device__ inline bf16x8 pack8(f32x4 a, f32x4 b) {
    bf16x8 r;
    r[0] = f2bf(a[0]); r[1] = f2bf(a[1]); r[2] = f2bf(a[2]); r[3] = f2bf(a[3]);
    r[4] = f2bf(b[0]); r[5] = f2bf(b[1]); r[6] = f2bf(b[2]); r[7] = f2bf(b[3]);
    return r;
}

// ---------------- k_prep: Kb = bf16(K); Vt = bf16(V^T) --------------------
// grid: 1024 (32 z x 32 j-tiles), block 256.
__global__ __launch_bounds__(256)
void k_prep(const float* __restrict__ kk, const float* __restrict__ v,
            short* __restrict__ Kb, short* __restrict__ Vt)
{
    const int bz = blockIdx.x >> 5;
    const int j0 = (blockIdx.x & 31) * 64;
    const int b = bz & 1, h = bz >> 1;
    const int tid = threadIdx.x;

    const int r = tid >> 2, seg = (tid & 3) * 16;
    const size_t kidx = ((size_t)((b * LQ + j0 + r) * NH + h)) * CD + seg;
    #pragma unroll
    for (int u = 0; u < 4; ++u) {
        f32x4 g = *(const f32x4*)(kk + kidx + u * 4);
        *(short4*)(Kb + kidx + u * 4) =
            make_short4(f2bf(g[0]), f2bf(g[1]), f2bf(g[2]), f2bf(g[3]));
    }

    const int rgrp = tid >> 4, c4 = tid & 15;
    const float* vp = v + ((size_t)((b * LQ + j0 + rgrp * 4) * NH + h)) * CD + c4 * 4;
    f32x4 va0 = *(const f32x4*)vp;
    f32x4 va1 = *(const f32x4*)(vp + NHC);
    f32x4 va2 = *(const f32x4*)(vp + 2 * NHC);
    f32x4 va3 = *(const f32x4*)(vp + 3 * NHC);
    #pragma unroll
    for (int cs = 0; cs < 4; ++cs) {
        *(short4*)(Vt + ((size_t)((b * NH + h) * CD + c4 * 4 + cs)) * LQ + j0 + rgrp * 4) =
            make_short4(f2bf(va0[cs]), f2bf(va1[cs]), f2bf(va2[cs]), f2bf(va3[cs]));
    }
}

// ---------------- k_A: sc = QK^T + edge ; inv = 1/rowsum(exp) -------------
// grid: 2048 (XCD-swizzled -> 64 i-stripes of 32 rows x 32 z), block 256.
// Wave w: rg = w>>1 (16-row group), jh = w&1 (j half, 1024 cols = 16 tiles).
__global__ __launch_bounds__(256, 8)
void k_A(const float* __restrict__ q, const short* __restrict__ Kb,
         const float* __restrict__ edge, const int* __restrict__ mask,
         float* __restrict__ sc, float* __restrict__ invout)
{
    __shared__ float lred[2][2][16];                // [rg][jh][mm]

    const int flat = blockIdx.x;
    const int L = (flat & 7) * 256 + (flat >> 3);   // XCD x owns 4 contiguous z
    const int z = L >> 6;
    const int i0 = (L & 63) * 32;
    const int b = z & 1, h = z >> 1;

    const int tid = threadIdx.x;
    const int wave = tid >> 6, lane = tid & 63;
    const int quad = lane >> 4, mm = lane & 15;
    const int rg = wave >> 1, jh = wave & 1;
    const int gi = i0 + rg * 16 + mm;               // this lane's query row
    const int jbase = jh * 1024;

    const float* qp = q + ((size_t)((b * LQ + gi) * NH + h)) * CD;
    bf16x8 qa0 = pack8(*(const f32x4*)(qp + quad * 8), *(const f32x4*)(qp + quad * 8 + 4));
    bf16x8 qa1 = pack8(*(const f32x4*)(qp + 32 + quad * 8), *(const f32x4*)(qp + 32 + quad * 8 + 4));

    const float* erow = edge + ((size_t)(h * LQ + gi)) * LQ + jbase;
    const int*   mrow = mask + ((size_t)(b * LQ + gi)) * LQ + jbase;
    const size_t srow = ((size_t)((b * NH + h) * LQ + gi)) * LQ + jbase;
    const short* kfb = Kb + (size_t)b * LQ * NHC + (size_t)h * CD + (size_t)jbase * NHC;

    f32x4 ev[4]; i32x4 mv[4];
    #pragma unroll
    for (int jt = 0; jt < 4; ++jt) {
        ev[jt] = *(const f32x4*)(erow + jt * 16 + quad * 4);
        mv[jt] = *(const i32x4*)(mrow + jt * 16 + quad * 4);
    }

    float lacc = 0.f;
    for (int jb = 0; jb < 16; ++jb) {
        const int j0 = jb * 64;
        f32x4 acc[4];
        #pragma unroll
        for (int jt = 0; jt < 4; ++jt) {
            const short* kr = kfb + (size_t)(j0 + jt * 16 + mm) * NHC + quad * 8;
            bf16x8 k0 = *(const bf16x8*)kr;
            bf16x8 k1 = *(const bf16x8*)(kr + 32);
            f32x4 a = {0.f, 0.f, 0.f, 0.f};
            a = __builtin_amdgcn_mfma_f32_16x16x32_bf16(k0, qa0, a, 0, 0, 0);
            a = __builtin_amdgcn_mfma_f32_16x16x32_bf16(k1, qa1, a, 0, 0, 0);
            acc[jt] = a;
        }
        #pragma unroll
        for (int jt = 0; jt < 4; ++jt) {
            f32x4 s4 = acc[jt] + ev[jt];
            *(f32x4*)(sc + srow + j0 + jt * 16 + quad * 4) = s4;
            lacc += (mv[jt][0] ? __expf(s4[0] * 0.125f) : 0.f)
                  + (mv[jt][1] ? __expf(s4[1] * 0.125f) : 0.f)
                  + (mv[jt][2] ? __expf(s4[2] * 0.125f) : 0.f)
                  + (mv[jt][3] ? __expf(s4[3] * 0.125f) : 0.f);
        }
        if (jb < 15) {
            #pragma unroll
            for (int jt = 0; jt < 4; ++jt) {
                ev[jt] = *(const f32x4*)(erow + j0 + 64 + jt * 16 + quad * 4);
                mv[jt] = *(const i32x4*)(mrow + j0 + 64 + jt * 16 + quad * 4);
            }
        }
    }

    // reduce over quads (j-subsets within this wave's half)
    lacc += __shfl_xor(lacc, 16, 64);
    lacc += __shfl_xor(lacc, 32, 64);
    if (quad == 0) lred[rg][jh][mm] = lacc;
    __syncthreads();
    if (jh == 0 && quad == 0) {
        const float tot = lred[rg][0][mm] + lred[rg][1][mm];
        invout[(size_t)(b * NH + h) * LQ + gi] = (tot > 0.f) ? 1.f / tot : 0.f;
    }
}

// ---------------- k_B: attn = exp(sc/8)*inv*mask ; ctx = attn @ V ---------
// Same geometry as k_A. Each wave PVs its j-half; pair (rg, jh=0/1) reduced
// through an 8KB LDS slab at kernel end.
__global__ __launch_bounds__(256, 8)
void k_B(const short* __restrict__ Vt, const int* __restrict__ mask,
         const float* __restrict__ invws, const float* __restrict__ sc,
         float* __restrict__ attn, float* __restrict__ ctx)
{
    __shared__ float red[2][16][64];                // [rg][row_local][col]

    const int flat = blockIdx.x;
    const int L = (flat & 7) * 256 + (flat >> 3);
    const int z = L >> 6;
    const int i0 = (L & 63) * 32;
    const int b = z & 1, h = z >> 1;

    const int tid = threadIdx.x;
    const int wave = tid >> 6, lane = tid & 63;
    const int quad = lane >> 4, mm = lane & 15;
    const int rg = wave >> 1, jh = wave & 1;
    const int gi = i0 + rg * 16 + mm;
    const int jbase = jh * 1024;

    const int*   mrow = mask + ((size_t)(b * LQ + gi)) * LQ + jbase;
    const size_t srow = ((size_t)((b * NH + h) * LQ + gi)) * LQ + jbase;
    const float  inv  = invws[(size_t)(b * NH + h) * LQ + gi];
    const short* vtb  = Vt + (size_t)(b * NH + h) * CD * LQ + jbase;   // + c*LQ + j

    f32x4 s0a = *(const f32x4*)(sc + srow + quad * 8);
    f32x4 s0b = *(const f32x4*)(sc + srow + quad * 8 + 4);
    f32x4 s1a = *(const f32x4*)(sc + srow + 32 + quad * 8);
    f32x4 s1b = *(const f32x4*)(sc + srow + 32 + quad * 8 + 4);
    i32x4 m0a = *(const i32x4*)(mrow + quad * 8);
    i32x4 m0b = *(const i32x4*)(mrow + quad * 8 + 4);
    i32x4 m1a = *(const i32x4*)(mrow + 32 + quad * 8);
    i32x4 m1b = *(const i32x4*)(mrow + 32 + quad * 8 + 4);

    f32x4 cacc[4] = { {0,0,0,0}, {0,0,0,0}, {0,0,0,0}, {0,0,0,0} };

    for (int jb = 0; jb < 16; ++jb) {
        const int j0 = jb * 64;
        f32x4 wa, wb2;
        wa[0] = m0a[0] ? __expf(s0a[0] * 0.125f) * inv : 0.f;
        wa[1] = m0a[1] ? __expf(s0a[1] * 0.125f) * inv : 0.f;
        wa[2] = m0a[2] ? __expf(s0a[2] * 0.125f) * inv : 0.f;
        wa[3] = m0a[3] ? __expf(s0a[3] * 0.125f) * inv : 0.f;
        wb2[0] = m0b[0] ? __expf(s0b[0] * 0.125f) * inv : 0.f;
        wb2[1] = m0b[1] ? __expf(s0b[1] * 0.125f) * inv : 0.f;
        wb2[2] = m0b[2] ? __expf(s0b[2] * 0.125f) * inv : 0.f;
        wb2[3] = m0b[3] ? __expf(s0b[3] * 0.125f) * inv : 0.f;
        *(f32x4*)(attn + srow + j0 + quad * 8) = wa;
        *(f32x4*)(attn + srow + j0 + quad * 8 + 4) = wb2;
        bf16x8 aw0 = pack8(wa, wb2);
        wa[0] = m1a[0] ? __expf(s1a[0] * 0.125f) * inv : 0.f;
        wa[1] = m1a[1] ? __expf(s1a[1] * 0.125f) * inv : 0.f;
        wa[2] = m1a[2] ? __expf(s1a[2] * 0.125f) * inv : 0.f;
        wa[3] = m1a[3] ? __expf(s1a[3] * 0.125f) * inv : 0.f;
        wb2[0] = m1b[0] ? __expf(s1b[0] * 0.125f) * inv : 0.f;
        wb2[1] = m1b[1] ? __expf(s1b[1] * 0.125f) * inv : 0.f;
        wb2[2] = m1b[2] ? __expf(s1b[2] * 0.125f) * inv : 0.f;
        wb2[3] = m1b[3] ? __expf(s1b[3] * 0.125f) * inv : 0.f;
        *(f32x4*)(attn + srow + j0 + 32 + quad * 8) = wa;
        *(f32x4*)(attn + srow + j0 + 32 + quad * 8 + 4) = wb2;
        bf16x8 aw1 = pack8(wa, wb2);

        if (jb < 15) {
            const int jn = j0 + 64;
            s0a = *(const f32x4*)(sc + srow + jn + quad * 8);
            s0b = *(const f32x4*)(sc + srow + jn + quad * 8 + 4);
            s1a = *(const f32x4*)(sc + srow + jn + 32 + quad * 8);
            s1b = *(const f32x4*)(sc + srow + jn + 32 + quad * 8 + 4);
            m0a = *(const i32x4*)(mrow + jn + quad * 8);
            m0b = *(const i32x4*)(mrow + jn + quad * 8 + 4);
            m1a = *(const i32x4*)(mrow + jn + 32 + quad * 8);
            m1b = *(const i32x4*)(mrow + jn + 32 + quad * 8 + 4);
        }

        #pragma unroll
        for (int nt = 0; nt < 4; ++nt) {
            const short* vr = vtb + (size_t)(nt * 16 + mm) * LQ + j0 + quad * 8;
            bf16x8 b0 = *(const bf16x8*)vr;
            bf16x8 b1 = *(const bf16x8*)(vr + 32);
            cacc[nt] = __builtin_amdgcn_mfma_f32_16x16x32_bf16(aw0, b0, cacc[nt], 0, 0, 0);
            cacc[nt] = __builtin_amdgcn_mfma_f32_16x16x32_bf16(aw1, b1, cacc[nt], 0, 0, 0);
        }
    }

    // cross-wave (j-half) reduction of the PV partials, then ctx store.
    if (jh == 1) {
        #pragma unroll
        for (int nt = 0; nt < 4; ++nt)
            #pragma unroll
            for (int reg = 0; reg < 4; ++reg)
                red[rg][quad * 4 + reg][nt * 16 + mm] = cacc[nt][reg];
    }
    __syncthreads();
    if (jh == 0) {
        const int irow = i0 + rg * 16 + quad * 4;
        #pragma unroll
        for (int nt = 0; nt < 4; ++nt) {
            const int c = nt * 16 + mm;
            #pragma unroll
            for (int reg = 0; reg < 4; ++reg) {
                const float s = cacc[nt][reg] + red[rg][quad * 4 + reg][c];
                ctx[((size_t)(b * LQ + irow + reg)) * NHC + h * CD + c] = s;
            }
        }
    }
}

extern "C" void kernel_launch(void* const* d_in, const int* in_sizes, int n_in,
                              void* d_out, int out_size, void* d_ws, size_t ws_size,
                              hipStream_t stream) {
    const float* q    = (const float*)d_in[0];
    const float* k    = (const float*)d_in[1];
    const float* v    = (const float*)d_in[2];
    const int*   mask = (const int*)d_in[3];    // bool -> int32 per harness contract
    const float* edge = (const float*)d_in[4];

    float* out = (float*)d_out;
    float* ctx = out;                            // 2*2048*1024
    float* sc  = out + 4194304;                  // scores (B,H,L,L)
    float* at  = sc + 134217728;                 // attn   (B,H,L,L)

    short* Kb  = (short*)d_ws;                   // 8 MB bf16 K
    short* Vt  = (short*)d_ws + 4194304;         // 8 MB bf16 V^T
    float* inv = (float*)((char*)d_ws + 16777216);  // 256 KB row inverses

    k_prep<<<dim3(1024), 256, 0, stream>>>(k, v, Kb, Vt);
    k_A   <<<dim3(2048), 256, 0, stream>>>(q, Kb, edge, mask, sc, inv);
    k_B   <<<dim3(2048), 256, 0, stream>>>(Vt, mask, inv, sc, at, ctx);
}

// Round 16
// 1661.978 us; speedup vs baseline: 1.0961x; 1.0961x over previous
//
#include <hip/hip_runtime.h>

// MultiHeadAttentionCell: B=2, L=2048, H=16, C=64, fp32 in/out.
// Outputs (concat in d_out): context_vec (B,L,H*C)=4194304 | scores (B,H,L,L)=134217728 | attn (B,H,L,L)=134217728
// scores = Q K^T + edge ; attn = softmax(where(mask, scores/8, -1e18)) * mask ; ctx = attn @ V
//
// Round 16: champion config (R10, 690us kernel / 1646 total) + phase-B single-barrier
// double-buffer (the only unexploited low-risk delta). After R7-R15 falsified bytes,
// barriers, occupancy(both directions), nt, conflicts, and contiguity as levers, the
// structure family's empirical rate is ~3.3TB/s; R10 is the floor config.
//   Phase A: QK^T sweep, dbuf K (1 barrier/iter), writes sc, accumulates row-sum l.
//   Phase B: recompute QK^T (bitwise-identical), attn = p*(1/l) once, PV -> ctx;
//            NOW dbuf K+V (1 barrier/iter, was 2).
// LDS: R11's verified SWZ [64]-row layout, 5 slabs x 8KB = 40KB -> 4 blocks/CU exact.
// Normal stores (nt regressed, R11). Raw lgkmcnt-only barriers (R7). K/V + edge/mask
// register prefetch. XCD chunk swizzle. No max-subtraction (scores/8 ~ N(0,1)+edge/8).

typedef __attribute__((ext_vector_type(8))) short bf16x8;  // 8 bf16 = 4 VGPRs
typedef __attribute__((ext_vector_type(4))) float f32x4;
typedef __attribute__((ext_vector_type(4))) int   i32x4;

#define LQ 2048
#define NH 16
#define CD 64
#define NHC (NH*CD)

__device__ inline short f2bf(float x) {
    union { float f; unsigned u; } v; v.f = x;
    unsigned r = v.u + 0x7FFFu + ((v.u >> 16) & 1u);   // RTNE
    return (short)(r >> 16);
}

__device__ inline bf16x8 pack8(f32x4 a, f32x4 b) {
    bf16x8 r;
    r[0] = f2bf(a[0]); r[1] = f2bf(a[1]); r[2] = f2bf(a[2]); r[3] = f2bf(a[3]);
    r[4] = f2bf(b[0]); r[5] = f2bf(b[1]); r[6] = f2bf(b[2]); r[7] = f2bf(b[3]);
    return r;
}

// LDS-visibility barrier WITHOUT __syncthreads' vmcnt(0) drain.
__device__ inline void lds_barrier() {
    asm volatile("s_waitcnt lgkmcnt(0)" ::: "memory");
    __builtin_amdgcn_s_barrier();
}

// XOR-swizzled address inside a [rows][64]-short bf16 tile (128 B rows).
// Same mapping on write and read (R11-verified).
#define SWZ(base, row, bytecol) \
    ((char*)(base) + ((row) * 128) + ((bytecol) ^ (((row) & 7) << 4)))

// LDS map (40960 B = 4 blocks/CU x 40KB = 160KB exact):
//   Ks slot0 @ 0      Ks slot1 @ 8192
//   Vt slot0 @ 16384  Vt slot1 @ 24576   (V^T: row=c, col=j_local)
//   Wt per wave @ 32768 + wave*2048
// Phase A: Ks dbuf. Phase B: Ks+Vt dbuf (1 barrier/iter).

// grid: 1024 (XCD-swizzled -> 32 i-tiles x 32 z=h*2+b), block 256 (4 waves).
__global__ __launch_bounds__(256, 4)
void k_attn(const float* __restrict__ q, const float* __restrict__ kk,
            const float* __restrict__ v, const int* __restrict__ mask,
            const float* __restrict__ edge,
            float* __restrict__ sc, float* __restrict__ attn,
            float* __restrict__ ctx)
{
    __shared__ __align__(16) char lds[40960];

    // XCD-chunk swizzle (bijective, 1024 % 8 == 0): XCD x gets 4 contiguous z-slices.
    const int flat = blockIdx.x;
    const int L = (flat & 7) * 128 + (flat >> 3);
    const int z = L >> 5;
    const int i0 = (L & 31) * 64;
    const int b = z & 1, h = z >> 1;

    const int tid = threadIdx.x;
    const int r = tid >> 2, seg = (tid & 3) * 16;   // K-staging mapping
    const int rgrp = tid >> 4, c4 = tid & 15;       // V-staging mapping (4x4 micro-tile)
    const int wave = tid >> 6, lane = tid & 63;
    const int quad = lane >> 4, mm = lane & 15;

    char* const wtb = lds + 32768 + wave * 2048;

    const int gi = i0 + wave * 16 + mm;            // this lane's query row
    // Q as B-fragment: B[k=quad*8+t][n=mm] = Q[gi][k]
    const float* qp = q + ((size_t)((b * LQ + gi) * NH + h)) * CD;
    bf16x8 qa0 = pack8(*(const f32x4*)(qp + quad * 8), *(const f32x4*)(qp + quad * 8 + 4));
    bf16x8 qa1 = pack8(*(const f32x4*)(qp + 32 + quad * 8), *(const f32x4*)(qp + 32 + quad * 8 + 4));

    const float* erow = edge + ((size_t)(h * LQ + gi)) * LQ;
    const int*   mrow = mask + ((size_t)(b * LQ + gi)) * LQ;
    const size_t srow = ((size_t)((b * NH + h) * LQ + gi)) * LQ;   // sc/attn row base

    const float* kbase = kk + ((size_t)((b * LQ + r) * NH + h)) * CD + seg;
    const float* vbase = v  + ((size_t)((b * LQ + rgrp * 4) * NH + h)) * CD + c4 * 4;
    const size_t kstep = (size_t)64 * NHC;         // 64 rows of K/V

    // edge/mask tile 0
    f32x4 ev[4]; i32x4 mv[4];
    #pragma unroll
    for (int jt = 0; jt < 4; ++jt) {
        ev[jt] = *(const f32x4*)(erow + jt * 16 + quad * 4);
        mv[jt] = *(const i32x4*)(mrow + jt * 16 + quad * 4);
    }

    // ================= Phase A: row sums + sc =================
    f32x4 kr[4];
    #pragma unroll
    for (int u = 0; u < 4; ++u) kr[u] = ((const f32x4*)kbase)[u];
    #pragma unroll
    for (int u = 0; u < 4; ++u)    // stage slot0 = K[0]
        *(short4*)SWZ(lds, r, 2 * seg + 8 * u) =
            make_short4(f2bf(kr[u][0]), f2bf(kr[u][1]), f2bf(kr[u][2]), f2bf(kr[u][3]));
    #pragma unroll
    for (int u = 0; u < 4; ++u) kr[u] = ((const f32x4*)(kbase + kstep))[u];   // K[1]
    lds_barrier();

    float lacc = 0.f;
    for (int jb = 0; jb < 32; ++jb) {
        const int j0 = jb * 64;
        const int cur = jb & 1;
        if (jb < 31) {     // stage next slot; issue K[jb+2]
            char* kn = lds + (cur ^ 1) * 8192;
            #pragma unroll
            for (int u = 0; u < 4; ++u)
                *(short4*)SWZ(kn, r, 2 * seg + 8 * u) =
                    make_short4(f2bf(kr[u][0]), f2bf(kr[u][1]), f2bf(kr[u][2]), f2bf(kr[u][3]));
            if (jb < 30) {
                const float* kp = kbase + kstep * (jb + 2);
                #pragma unroll
                for (int u = 0; u < 4; ++u) kr[u] = ((const f32x4*)kp)[u];
            }
        }
        // swapped QK^T: acc[jt][reg] = S[gi][j0 + jt*16 + quad*4 + reg]
        char* const kb = lds + cur * 8192;
        f32x4 acc[4];
        #pragma unroll
        for (int jt = 0; jt < 4; ++jt) {
            bf16x8 k0 = *(const bf16x8*)SWZ(kb, jt * 16 + mm, 16 * quad);
            bf16x8 k1 = *(const bf16x8*)SWZ(kb, jt * 16 + mm, 64 + 16 * quad);
            f32x4 a = {0.f, 0.f, 0.f, 0.f};
            a = __builtin_amdgcn_mfma_f32_16x16x32_bf16(k0, qa0, a, 0, 0, 0);
            a = __builtin_amdgcn_mfma_f32_16x16x32_bf16(k1, qa1, a, 0, 0, 0);
            acc[jt] = a;
        }
        #pragma unroll
        for (int jt = 0; jt < 4; ++jt) {
            f32x4 s4 = acc[jt] + ev[jt];
            *(f32x4*)(sc + srow + j0 + jt * 16 + quad * 4) = s4;
            lacc += (mv[jt][0] ? __expf(s4[0] * 0.125f) : 0.f)
                  + (mv[jt][1] ? __expf(s4[1] * 0.125f) : 0.f)
                  + (mv[jt][2] ? __expf(s4[2] * 0.125f) : 0.f)
                  + (mv[jt][3] ? __expf(s4[3] * 0.125f) : 0.f);
        }
        if (jb < 31) {
            #pragma unroll
            for (int jt = 0; jt < 4; ++jt) {
                ev[jt] = *(const f32x4*)(erow + j0 + 64 + jt * 16 + quad * 4);
                mv[jt] = *(const i32x4*)(mrow + j0 + 64 + jt * 16 + quad * 4);
            }
        }
        lds_barrier();     // dbuf: one barrier covers "next staged" + "cur reads done"
    }

    // row total over the 4 quads sharing this mm -> every lane holds its row's inv
    lacc += __shfl_xor(lacc, 16, 64);
    lacc += __shfl_xor(lacc, 32, 64);
    const float inv = (lacc > 0.f) ? 1.f / lacc : 0.f;   // l==0 iff all-masked row -> 0

    // ================= Phase B: attn (normalized) + PV, dbuf K+V ==========
    f32x4 vr[4];
    #pragma unroll
    for (int u = 0; u < 4; ++u) kr[u] = ((const f32x4*)kbase)[u];
    #pragma unroll
    for (int t = 0; t < 4; ++t) vr[t] = *(const f32x4*)(vbase + t * NHC);
    #pragma unroll
    for (int jt = 0; jt < 4; ++jt) {
        ev[jt] = *(const f32x4*)(erow + jt * 16 + quad * 4);
        mv[jt] = *(const i32x4*)(mrow + jt * 16 + quad * 4);
    }
    // stage slot0 = (K[0], V[0])
    #pragma unroll
    for (int u = 0; u < 4; ++u)
        *(short4*)SWZ(lds, r, 2 * seg + 8 * u) =
            make_short4(f2bf(kr[u][0]), f2bf(kr[u][1]), f2bf(kr[u][2]), f2bf(kr[u][3]));
    #pragma unroll
    for (int cs = 0; cs < 4; ++cs)
        *(short4*)SWZ(lds + 16384, c4 * 4 + cs, 8 * rgrp) =
            make_short4(f2bf(vr[0][cs]), f2bf(vr[1][cs]), f2bf(vr[2][cs]), f2bf(vr[3][cs]));
    { // issue jb=1
        const float* kp = kbase + kstep;
        const float* vp = vbase + kstep;
        #pragma unroll
        for (int u = 0; u < 4; ++u) kr[u] = ((const f32x4*)kp)[u];
        #pragma unroll
        for (int t = 0; t < 4; ++t) vr[t] = *(const f32x4*)(vp + t * NHC);
    }
    lds_barrier();

    f32x4 cacc[4] = { {0,0,0,0}, {0,0,0,0}, {0,0,0,0}, {0,0,0,0} };

    for (int jb = 0; jb < 32; ++jb) {
        const int j0 = jb * 64;
        const int cur = jb & 1;
        if (jb < 31) {     // stage next slot (K+V); issue jb+2
            char* kn = lds + (cur ^ 1) * 8192;
            char* vn = lds + 16384 + (cur ^ 1) * 8192;
            #pragma unroll
            for (int u = 0; u < 4; ++u)
                *(short4*)SWZ(kn, r, 2 * seg + 8 * u) =
                    make_short4(f2bf(kr[u][0]), f2bf(kr[u][1]), f2bf(kr[u][2]), f2bf(kr[u][3]));
            #pragma unroll
            for (int cs = 0; cs < 4; ++cs)
                *(short4*)SWZ(vn, c4 * 4 + cs, 8 * rgrp) =
                    make_short4(f2bf(vr[0][cs]), f2bf(vr[1][cs]), f2bf(vr[2][cs]), f2bf(vr[3][cs]));
            if (jb < 30) {
                const float* kp = kbase + kstep * (jb + 2);
                const float* vp = vbase + kstep * (jb + 2);
                #pragma unroll
                for (int u = 0; u < 4; ++u) kr[u] = ((const f32x4*)kp)[u];
                #pragma unroll
                for (int t = 0; t < 4; ++t) vr[t] = *(const f32x4*)(vp + t * NHC);
            }
        }

        char* const kb = lds + cur * 8192;
        f32x4 acc[4];                  // identical MFMA as phase A -> bitwise-same s4
        #pragma unroll
        for (int jt = 0; jt < 4; ++jt) {
            bf16x8 k0 = *(const bf16x8*)SWZ(kb, jt * 16 + mm, 16 * quad);
            bf16x8 k1 = *(const bf16x8*)SWZ(kb, jt * 16 + mm, 64 + 16 * quad);
            f32x4 a = {0.f, 0.f, 0.f, 0.f};
            a = __builtin_amdgcn_mfma_f32_16x16x32_bf16(k0, qa0, a, 0, 0, 0);
            a = __builtin_amdgcn_mfma_f32_16x16x32_bf16(k1, qa1, a, 0, 0, 0);
            acc[jt] = a;
        }

        // epilogue: attn = normalized w, Wt = bf16(w) for PV
        #pragma unroll
        for (int jt = 0; jt < 4; ++jt) {
            f32x4 s4 = acc[jt] + ev[jt];
            f32x4 w;
            w[0] = mv[jt][0] ? __expf(s4[0] * 0.125f) * inv : 0.f;
            w[1] = mv[jt][1] ? __expf(s4[1] * 0.125f) * inv : 0.f;
            w[2] = mv[jt][2] ? __expf(s4[2] * 0.125f) * inv : 0.f;
            w[3] = mv[jt][3] ? __expf(s4[3] * 0.125f) * inv : 0.f;
            *(f32x4*)(attn + srow + j0 + jt * 16 + quad * 4) = w;
            *(short4*)SWZ(wtb, mm, 32 * jt + 8 * quad) =
                make_short4(f2bf(w[0]), f2bf(w[1]), f2bf(w[2]), f2bf(w[3]));
        }

        if (jb < 31) {
            #pragma unroll
            for (int jt = 0; jt < 4; ++jt) {
                ev[jt] = *(const f32x4*)(erow + j0 + 64 + jt * 16 + quad * 4);
                mv[jt] = *(const i32x4*)(mrow + j0 + 64 + jt * 16 + quad * 4);
            }
        }

        // PV: A = Wt row mm (wave-internal RAW), B = Vt[cur].
        char* const vb = lds + 16384 + cur * 8192;
        #pragma unroll
        for (int kt = 0; kt < 2; ++kt) {
            bf16x8 aw = *(const bf16x8*)SWZ(wtb, mm, 64 * kt + 16 * quad);
            #pragma unroll
            for (int nt = 0; nt < 4; ++nt) {
                bf16x8 bbv = *(const bf16x8*)SWZ(vb, nt * 16 + mm, 64 * kt + 16 * quad);
                cacc[nt] = __builtin_amdgcn_mfma_f32_16x16x32_bf16(aw, bbv, cacc[nt], 0, 0, 0);
            }
        }
        lds_barrier();     // dbuf: one barrier covers "next staged" + "cur reads done"
    }

    // ctx: C-layout (col c = nt*16+mm, row i = quad*4+reg); already normalized
    const int irow = i0 + wave * 16 + quad * 4;
    #pragma unroll
    for (int nt = 0; nt < 4; ++nt) {
        const int c = nt * 16 + mm;
        #pragma unroll
        for (int reg = 0; reg < 4; ++reg) {
            const int i = irow + reg;
            ctx[((size_t)(b * LQ + i)) * NHC + h * CD + c] = cacc[nt][reg];
        }
    }
}

extern "C" void kernel_launch(void* const* d_in, const int* in_sizes, int n_in,
                              void* d_out, int out_size, void* d_ws, size_t ws_size,
                              hipStream_t stream) {
    const float* q    = (const float*)d_in[0];
    const float* k    = (const float*)d_in[1];
    const float* v    = (const float*)d_in[2];
    const int*   mask = (const int*)d_in[3];    // bool -> int32 per harness contract
    const float* edge = (const float*)d_in[4];

    float* out = (float*)d_out;
    float* ctx = out;                            // 2*2048*1024
    float* sc  = out + 4194304;                  // scores (B,H,L,L)
    float* at  = sc + 134217728;                 // attn   (B,H,L,L)

    k_attn<<<dim3(1024), 256, 0, stream>>>(q, k, v, mask, edge, sc, at, ctx);
}